// Round 7
// baseline (2231.583 us; speedup 1.0000x reference)
//
#include <hip/hip_runtime.h>
#include <cmath>
#include <cstdint>

#define NT 256
#define EG0 1024          // grid for full-E passes
#define EG1 512           // grid for compacted passes
#define MAX_ROUND 16      // rounds 0..15 (round0 specialized, 1..15 gated)
#define SCAN_T 32
#define SCAN_IPB (NT*SCAN_T)

// ---------- helpers ----------

// Block-aggregated stream compaction append: ONE global atomic per block-tile.
// All threads of the block must call together (block-uniform loop).
__device__ __forceinline__ int block_append(int* cursor, bool pred, int* s_w){
  int wid  = threadIdx.x >> 6;
  int lane = threadIdx.x & 63;
  unsigned long long m = __ballot(pred);
  int cnt = __popcll(m);
  if(lane==0) s_w[wid]=cnt;
  __syncthreads();
  if(threadIdx.x==0){
    int t0=s_w[0], t1=s_w[1], t2=s_w[2], t3=s_w[3];
    int tot=t0+t1+t2+t3;
    int base = tot ? atomicAdd(cursor, tot) : 0;
    s_w[0]=base; s_w[1]=base+t0; s_w[2]=base+t0+t1; s_w[3]=base+t0+t1+t2;
  }
  __syncthreads();
  int pos = s_w[wid] + __popcll(m & ((1ull<<lane)-1ull));
  __syncthreads();
  return pos;
}

// ---------- init ----------

__global__ void k_init(int* a, int* b, int n){
  int v = blockIdx.x*NT + threadIdx.x;
  if(v<n){ a[v]=v; b[v]=v; }
}

// ---------- round 0 (full edge arrays) ----------

// hop1 with a == arange: source value IS row index
__global__ void k_hop0(int* b, const int* __restrict__ row,
                       const int* __restrict__ col, int E){
  int stride = gridDim.x*NT;
  for(int e = blockIdx.x*NT + threadIdx.x; e<E; e+=stride){
    int s = row[e];
    if(s < b[col[e]]) atomicMin(&b[col[e]], s);
  }
}

// hop2 fused with self-fold
__global__ void k_hop0f(int* a, const int* b, const int* __restrict__ row,
                        const int* __restrict__ col, int n, int E){
  int stride = gridDim.x*NT;
  int total = n + E;
  for(int i = blockIdx.x*NT + threadIdx.x; i<total; i+=stride){
    if(i<n){
      if(b[i] < a[i]) atomicMin(&a[i], b[i]);
    } else {
      int e = i-n;
      int s = b[row[e]];
      if(s < a[col[e]]) atomicMin(&a[col[e]], s);
    }
  }
}

// dil1: new-MIS rows seed d2 (epoch) + cover
__global__ void k_dil0(const int* a, int* d2, int* cover, const int* __restrict__ row,
                       const int* __restrict__ col, int E, int ep){
  int stride = gridDim.x*NT;
  for(int e = blockIdx.x*NT + threadIdx.x; e<E; e+=stride){
    int r = row[e];
    if(a[r]==r){
      int cc = col[e];
      d2[r]=ep;  cover[r]=1;
      d2[cc]=ep; cover[cc]=1;
    }
  }
}

// dil2 + SUPERSET edge compaction fused. Stale cover reads only keep extra
// edges (covered endpoints are inert: rank n) -> dropped by next round's filter.
// A drop requires both covers read 1 => final 1 => never wrong-drops.
__global__ void k_dil20c(const int* a, const int* d2, int* cover,
                         const int* __restrict__ row, const int* __restrict__ col,
                         int E, int ep, int2* Ld, int* lcnt1){
  __shared__ int s_w[4];
  long nth = (long)gridDim.x*NT;
  for(long base=(long)blockIdx.x*NT; base<E; base+=nth){
    int e=(int)base+threadIdx.x;
    bool keep=false; int2 ed;
    if(e<E){
      ed = make_int2(row[e], col[e]);
      int cx = cover[ed.x];
      if((d2[ed.x]==ep || a[ed.x]==ed.x) && !cover[ed.y]) cover[ed.y]=1;
      int cy = cover[ed.y];
      keep = (!cx) || (!cy);
    }
    int pos = block_append(lcnt1, keep, s_w);
    if(keep) Ld[pos]=ed;
  }
}

// node finalize round 0: fold mis, reset ranks from FINAL cover, build U1
__global__ void k_finnode0(int* a, int* b, int* mis, int* cover, int n,
                           int* U1, int* rcnt0){
  __shared__ int s_w[4];
  long nth = (long)gridDim.x*NT;
  for(long base=(long)blockIdx.x*NT; base<n; base+=nth){
    int v = (int)base + threadIdx.x;
    bool unc=false;
    if(v<n){
      int nw = (a[v]==v);
      int cov = cover[v] | nw;
      if(nw){ mis[v]=1; if(!cover[v]) cover[v]=1; }
      int val = cov ? n : v;
      a[v]=val; b[v]=val;
      unc = !cov;
    }
    int pos = block_append(rcnt0, unc, s_w);
    if(unc) U1[pos]=v;
  }
}

// ---------- rounds >=1 (compacted list, frontier list, gated) ----------

__global__ void k_hop1(int* b, const int* a, const int2* L, const int* pE,
                       const int* gate){
  if(*gate==0) return;
  int E = *pE;
  int stride = gridDim.x*NT;
  for(int e = blockIdx.x*NT + threadIdx.x; e<E; e+=stride){
    int2 ed = L[e];
    int s = a[ed.x];
    if(s < b[ed.y]) atomicMin(&b[ed.y], s);
  }
}

__global__ void k_hop1f(int* a, const int* b, const int2* L, const int* pE,
                        const int* U, const int* pU, const int* gate){
  if(*gate==0) return;
  int E = *pE, un = *pU;
  int total = un + E;
  int stride = gridDim.x*NT;
  for(int i = blockIdx.x*NT + threadIdx.x; i<total; i+=stride){
    if(i<un){
      int u = U[i];
      if(b[u] < a[u]) atomicMin(&a[u], b[u]);
    } else {
      int2 ed = L[i-un];
      int s = b[ed.x];
      if(s < a[ed.y]) atomicMin(&a[ed.y], s);
    }
  }
}

__global__ void k_dil11(const int* a, int* d2, int* cover, int* mis, const int2* L,
                        const int* pE, const int* U, const int* pU, const int* gate, int ep){
  if(*gate==0) return;
  int E = *pE, un = *pU;
  int total = un + E;
  int stride = gridDim.x*NT;
  for(int i = blockIdx.x*NT + threadIdx.x; i<total; i+=stride){
    if(i<un){
      int u = U[i];
      if(a[u]==u){ mis[u]=1; cover[u]=1; d2[u]=ep; }
    } else {
      int2 ed = L[i-un];
      if(a[ed.x]==ed.x){ d2[ed.x]=ep; cover[ed.x]=1; d2[ed.y]=ep; cover[ed.y]=1; }
    }
  }
}

// dil2 + superset compaction (gated), list version
__global__ void k_dil21c(const int* a, const int* d2, int* cover,
                         const int2* Ls, const int* pE, int ep,
                         int2* Ld, int* lcntD, const int* gate){
  if(*gate==0) return;
  __shared__ int s_w[4];
  int E = *pE;
  long nth = (long)gridDim.x*NT;
  for(long base=(long)blockIdx.x*NT; base<E; base+=nth){
    int e=(int)base+threadIdx.x;
    bool keep=false; int2 ed;
    if(e<E){
      ed = Ls[e];
      int cx = cover[ed.x];
      if((d2[ed.x]==ep || a[ed.x]==ed.x) && !cover[ed.y]) cover[ed.y]=1;
      int cy = cover[ed.y];
      keep = (!cx) || (!cy);
    }
    int pos = block_append(lcntD, keep, s_w);
    if(keep) Ld[pos]=ed;
  }
}

// node finalize rounds >=1: reset ALL nodes from final cover (tiny n-pass),
// compact frontier Us -> Ud, count rcnt
__global__ void k_finnode1(int* a, int* b, const int* cover, int n,
                           const int* Us, const int* pU, int* Ud, int* rcntD,
                           const int* gate){
  if(*gate==0) return;
  __shared__ int s_w[4];
  long nth = (long)gridDim.x*NT;
  int stride = gridDim.x*NT;
  for(int v = blockIdx.x*NT + threadIdx.x; v<n; v+=stride){
    int val = cover[v] ? n : v;
    a[v]=val; b[v]=val;
  }
  int un = *pU;
  for(long base=(long)blockIdx.x*NT; base<un; base+=nth){
    int i=(int)base+threadIdx.x;
    bool unc=false; int u=0;
    if(i<un){ u=Us[i]; unc = !cover[u]; }
    int pos = block_append(rcntD, unc, s_w);
    if(unc) Ud[pos]=u;
  }
}

// ---------- cluster phase ----------

__global__ void k_cluster_init(const int* mis, int* a, int* b, int n){
  int v = blockIdx.x*NT + threadIdx.x;
  if(v<n){ int m = mis[v] ? v : n; a[v]=m; b[v]=m; }
}

__global__ void k_chop1(int* b, const int* a, const int* __restrict__ row,
                        const int* __restrict__ col, int n, int E){
  int stride = gridDim.x*NT;
  for(int e = blockIdx.x*NT + threadIdx.x; e<E; e+=stride){
    int s = a[row[e]];
    if(s < n && s < b[col[e]]) atomicMin(&b[col[e]], s);
  }
}

__global__ void k_chop2f(int* a, const int* b, const int* __restrict__ row,
                         const int* __restrict__ col, int n, int E){
  int stride = gridDim.x*NT;
  int total = n + E;
  for(int i = blockIdx.x*NT + threadIdx.x; i<total; i+=stride){
    if(i<n){
      if(b[i] < a[i]) atomicMin(&a[i], b[i]);
    } else {
      int e = i-n;
      int s = b[row[e]];
      if(s < n && s < a[col[e]]) atomicMin(&a[col[e]], s);
    }
  }
}

__global__ void k_mark(const int* mr, const int* mis, int* present, int* cmis, int n){
  int v = blockIdx.x*NT + threadIdx.x;
  int m = 0;
  if(v<n){
    int r = mr[v];
    if(r<n) present[r]=1;
    m = mis[v];
  }
  __shared__ int sh[NT];
  sh[threadIdx.x]=m; __syncthreads();
  for(int off=NT/2; off>0; off>>=1){
    if(threadIdx.x<off) sh[threadIdx.x]+=sh[threadIdx.x+off];
    __syncthreads();
  }
  if(threadIdx.x==0 && sh[0]) atomicAdd(cmis, sh[0]);
}

// ---------- generic scan ----------

__global__ void k_scan1(const int* A, int M, int* bsum){
  int t = threadIdx.x;
  long base = (long)blockIdx.x*SCAN_IPB + (long)t*SCAN_T;
  int s = 0;
  #pragma unroll
  for(int j=0;j<SCAN_T;j++){ long i=base+j; if(i<M) s += A[i]; }
  __shared__ int sh[NT];
  sh[t]=s; __syncthreads();
  for(int off=NT/2; off>0; off>>=1){ if(t<off) sh[t]+=sh[t+off]; __syncthreads(); }
  if(t==0) bsum[blockIdx.x]=sh[0];
}

__global__ void k_scan2(const int* bsum, int* bscan, int B, int* totalOut){
  __shared__ int sh[NT];
  int t = threadIdx.x;
  int carry = 0;
  for(int base=0; base<B; base+=NT){
    int i = base+t;
    int v = (i<B) ? bsum[i] : 0;
    sh[t]=v; __syncthreads();
    for(int off=1; off<NT; off<<=1){
      int x=0; if(t>=off) x=sh[t-off];
      __syncthreads();
      sh[t]+=x; __syncthreads();
    }
    int incl = sh[t];
    if(i<B) bscan[i] = carry + incl - v;
    carry += sh[NT-1];
    __syncthreads();
  }
  if(t==0 && totalOut) *totalOut = carry;
}

__global__ void k_scan3(const int* A, int M, const int* bscan, int* pref){
  int t = threadIdx.x;
  long base = (long)blockIdx.x*SCAN_IPB + (long)t*SCAN_T;
  int s = 0;
  #pragma unroll
  for(int j=0;j<SCAN_T;j++){ long i=base+j; if(i<M) s += A[i]; }
  __shared__ int sh[NT];
  sh[t]=s; __syncthreads();
  for(int off=1; off<NT; off<<=1){
    int x=0; if(t>=off) x=sh[t-off];
    __syncthreads();
    sh[t]+=x; __syncthreads();
  }
  int run = bscan[blockIdx.x] + (sh[t]-s);
  for(int j=0;j<SCAN_T;j++){
    long i=base+j;
    if(i<M){ pref[i]=run; run += A[i]; }
  }
}

// ---------- clustering & pooling ----------

__global__ void k_assign(const int* mr, const int* pref, int* cl, int* ccount, int n){
  int v = blockIdx.x*NT + threadIdx.x;
  if(v<n){
    int r = mr[v];
    int cid = (r<n) ? pref[r] : 0;
    cl[v]=cid;
    atomicAdd(&ccount[cid],1);
  }
}

__global__ void k_scatter_nodes(const int* cl, const int* cstart, int* cursor, int* nodeList, int n){
  int v = blockIdx.x*NT + threadIdx.x;
  if(v<n){
    int cid = cl[v];
    int pos = cstart[cid] + atomicAdd(&cursor[cid],1);
    nodeList[pos]=v;
  }
}

__global__ void k_pool_x(const float* __restrict__ x, const int* nodeList, const int* cstart,
                         const int* ccount, const int* scal, float* out, long out_size){
  int c = scal[0], U = scal[1];
  int t = threadIdx.x;
  for(int cid=blockIdx.x; cid<c; cid+=gridDim.x){
    float s0=0.f, s1=0.f, s2=0.f, s3=0.f;
    if(cid<U){
      int st = cstart[cid], cn = ccount[cid];
      int i=0;
      for(; i+3<cn; i+=4){
        int n0=nodeList[st+i], n1=nodeList[st+i+1], n2=nodeList[st+i+2], n3=nodeList[st+i+3];
        s0 += x[(size_t)n0*256 + t];
        s1 += x[(size_t)n1*256 + t];
        s2 += x[(size_t)n2*256 + t];
        s3 += x[(size_t)n3*256 + t];
      }
      for(; i<cn; i++) s0 += x[(size_t)nodeList[st+i]*256 + t];
      s0 += s1+s2+s3;
    }
    long idx = (long)cid*256 + t;
    if(idx < out_size) out[idx]=s0;
  }
}

__global__ void k_edge_pool(const int* __restrict__ row, const int* __restrict__ col,
                            const float* __restrict__ attr, const int* cl,
                            const int* scal, float* dense, unsigned int* bits, int E, long CMsq){
  int c = scal[0];
  int stride = gridDim.x*NT;
  for(int e = blockIdx.x*NT + threadIdx.x; e<E; e+=stride){
    long key = (long)cl[row[e]]*c + cl[col[e]];
    if(key < CMsq){
      unsafeAtomicAdd(&dense[key], attr[e]);       // native global_atomic_add_f32
      unsigned int msk = 1u<<((int)key&31);
      if(!(bits[key>>5] & msk)) atomicOr(&bits[key>>5], msk);   // monotone read-skip
    }
  }
}

__global__ void k_cscan1(const unsigned int* bits, const int* scal, int* bsum, long CMsq){
  int c = scal[0];
  long M = (long)c*c; if(M>CMsq) M=CMsq;
  int t = threadIdx.x;
  long base = (long)blockIdx.x*SCAN_IPB + (long)t*SCAN_T;
  int s = 0;
  if(base < M && c > 0){
    int r = (int)(base / c);
    int q = (int)(base - (long)r*c);
    for(int j=0;j<SCAN_T;j++){
      long i=base+j;
      if(i<M){
        if(((bits[i>>5]>>((int)i&31))&1u) && r!=q) s++;
      }
      if(++q==c){ q=0; r++; }
    }
  }
  __shared__ int sh[NT];
  sh[t]=s; __syncthreads();
  for(int off=NT/2; off>0; off>>=1){ if(t<off) sh[t]+=sh[t+off]; __syncthreads(); }
  if(t==0) bsum[blockIdx.x]=sh[0];
}

__global__ void k_cemit(const unsigned int* bits, const float* dense, const int* scal,
                        const int* bscan, float* out, long out_size, long CMsq){
  int c = scal[0]; int P = scal[2];
  long M = (long)c*c; if(M>CMsq) M=CMsq;
  long xoff = (long)c*256;
  int t = threadIdx.x;
  long base = (long)blockIdx.x*SCAN_IPB + (long)t*SCAN_T;
  int s = 0;
  int r0=0,q0=0;
  if(base < M && c > 0){
    r0 = (int)(base / c);
    q0 = (int)(base - (long)r0*c);
    int r=r0, q=q0;
    for(int j=0;j<SCAN_T;j++){
      long i=base+j;
      if(i<M){
        if(((bits[i>>5]>>((int)i&31))&1u) && r!=q) s++;
      }
      if(++q==c){ q=0; r++; }
    }
  }
  __shared__ int sh[NT];
  sh[t]=s; __syncthreads();
  for(int off=1; off<NT; off<<=1){
    int x=0; if(t>=off) x=sh[t-off];
    __syncthreads();
    sh[t]+=x; __syncthreads();
  }
  int run = bscan[blockIdx.x] + (sh[t]-s);
  if(base < M && c > 0){
    int r=r0, q=q0;
    for(int j=0;j<SCAN_T;j++){
      long i=base+j;
      if(i<M && ((bits[i>>5]>>((int)i&31))&1u) && r!=q){
        long o0 = xoff + run;
        long o1 = xoff + (long)P + run;
        long o2 = xoff + 2L*(long)P + run;
        if(o0<out_size) out[o0]=(float)r;
        if(o1<out_size) out[o1]=(float)q;
        if(o2<out_size) out[o2]=dense[i];
        run++;
      }
      if(++q==c){ q=0; r++; }
    }
  }
}

// ---------- host ----------

extern "C" void kernel_launch(void* const* d_in, const int* in_sizes, int n_in,
                              void* d_out, int out_size, void* d_ws, size_t ws_size,
                              hipStream_t stream){
  (void)n_in;
  const float* x     = (const float*)d_in[0];
  const int*   eidx  = (const int*)d_in[1];
  const float* eattr = (const float*)d_in[2];
  const int D = 256;
  int n = in_sizes[0]/D;
  int E = in_sizes[1]/2;
  const int* row = eidx;
  const int* col = eidx + E;

  char* p = (char*)d_ws;
  auto alloc = [&](size_t bytes)->char*{ char* r=p; p += (bytes+255)&~(size_t)255; return r; };
  int2* LA   = (int2*)alloc((size_t)E*8);
  int2* LB   = (int2*)alloc((size_t)E*8);
  int* a     = (int*)alloc((size_t)n*4);
  int* b     = (int*)alloc((size_t)n*4);
  int* cl    = (int*)alloc((size_t)n*4);
  int* nodeList = (int*)alloc((size_t)n*4);
  int* pref  = (int*)alloc((size_t)n*4);
  int* U1    = (int*)alloc((size_t)n*4);
  int* U2    = (int*)alloc((size_t)n*4);
  int* bsum  = (int*)alloc(4096*4);
  int* bscan = (int*)alloc(4096*4);
  char* zstart = p;                         // zeroed each call
  int* mis     = (int*)alloc((size_t)n*4);
  int* cover   = (int*)alloc((size_t)n*4);
  int* d2      = (int*)alloc((size_t)n*4);
  int* present = (int*)alloc((size_t)n*4);
  int* ccount  = (int*)alloc((size_t)n*4);
  int* cursor  = (int*)alloc((size_t)n*4);
  int* rcnt    = (int*)alloc((MAX_ROUND+2)*4);
  int* lcnt    = (int*)alloc((MAX_ROUND+2)*4);
  int* scal    = (int*)alloc(64);              // [0]=c, [1]=U, [2]=P

  size_t used   = (size_t)(p-(char*)d_ws);
  size_t remain = (ws_size > used+4096) ? ws_size-used-4096 : 0;
  size_t cells  = remain/5;
  long CM = (long)std::sqrt((double)cells);
  while(CM>1 && CM*CM > (long)cells) CM--;
  if(CM>4096) CM=4096;
  if(CM<1) CM=1;
  long CMsq = CM*CM;
  unsigned int* bits = (unsigned int*)alloc(((size_t)CMsq/32 + 2)*4);
  float* dense       = (float*)alloc((size_t)CMsq*4);
  size_t zbytes = (size_t)(p - zstart);
  hipMemsetAsync(zstart, 0, zbytes, stream);

  int NB  = (n+NT-1)/NT;
  int NBs = (n+SCAN_IPB-1)/SCAN_IPB;
  int CB  = (int)((CMsq+SCAN_IPB-1)/SCAN_IPB);

  // ---- round 0 (full graph) ----
  k_init    <<<NB,NT,0,stream>>>(a,b,n);
  k_hop0    <<<EG0,NT,0,stream>>>(b,row,col,E);
  k_hop0f   <<<EG0,NT,0,stream>>>(a,b,row,col,n,E);
  k_dil0    <<<EG0,NT,0,stream>>>(a,d2,cover,row,col,E,1);
  k_dil20c  <<<EG0,NT,0,stream>>>(a,d2,cover,row,col,E,1,LB,&lcnt[1]);
  k_finnode0<<<EG0,NT,0,stream>>>(a,b,mis,cover,n,U1,&rcnt[0]);

  // ---- rounds 1..MAX_ROUND-1 (compacted, gated on rcnt[r-1]) ----
  for(int r=1; r<MAX_ROUND; ++r){
    int2* Ls = (r&1) ? LB : LA;
    int2* Ld = (r&1) ? LA : LB;
    int*  Us = (r&1) ? U1 : U2;
    int*  Ud = (r&1) ? U2 : U1;
    int ep = r+1;
    k_hop1    <<<EG1,NT,0,stream>>>(b,a,Ls,&lcnt[r],&rcnt[r-1]);
    k_hop1f   <<<EG1,NT,0,stream>>>(a,b,Ls,&lcnt[r],Us,&rcnt[r-1],&rcnt[r-1]);
    k_dil11   <<<EG1,NT,0,stream>>>(a,d2,cover,mis,Ls,&lcnt[r],Us,&rcnt[r-1],&rcnt[r-1],ep);
    k_dil21c  <<<EG1,NT,0,stream>>>(a,d2,cover,Ls,&lcnt[r],ep,Ld,&lcnt[r+1],&rcnt[r-1]);
    k_finnode1<<<EG1,NT,0,stream>>>(a,b,cover,n,Us,&rcnt[r-1],Ud,&rcnt[r],&rcnt[r-1]);
  }

  // ---- cluster propagation ----
  k_cluster_init<<<NB,NT,0,stream>>>(mis,a,b,n);
  k_chop1 <<<EG0,NT,0,stream>>>(b,a,row,col,n,E);
  k_chop2f<<<EG0,NT,0,stream>>>(a,b,row,col,n,E);

  // ---- unique -> cluster ids ----
  k_mark <<<NB,NT,0,stream>>>(a,mis,present,scal,n);
  k_scan1<<<NBs,NT,0,stream>>>(present,n,bsum);
  k_scan2<<<1,NT,0,stream>>>(bsum,bscan,NBs,scal+1);
  k_scan3<<<NBs,NT,0,stream>>>(present,n,bscan,pref);
  k_assign<<<NB,NT,0,stream>>>(a,pref,cl,ccount,n);

  // ---- counting sort by cluster ----
  k_scan1<<<NBs,NT,0,stream>>>(ccount,n,bsum);
  k_scan2<<<1,NT,0,stream>>>(bsum,bscan,NBs,nullptr);
  k_scan3<<<NBs,NT,0,stream>>>(ccount,n,bscan,pref);
  k_scatter_nodes<<<NB,NT,0,stream>>>(cl,pref,cursor,nodeList,n);

  // ---- x_pooled ----
  k_pool_x<<<1024,NT,0,stream>>>(x,nodeList,pref,ccount,scal,(float*)d_out,(long)out_size);

  // ---- pooled adjacency ----
  k_edge_pool<<<EG0,NT,0,stream>>>(row,col,eattr,cl,scal,dense,bits,E,CMsq);
  k_cscan1<<<CB,NT,0,stream>>>(bits,scal,bsum,CMsq);
  k_scan2 <<<1,NT,0,stream>>>(bsum,bscan,CB,scal+2);
  k_cemit <<<CB,NT,0,stream>>>(bits,dense,scal,bscan,(float*)d_out,(long)out_size,CMsq);
}

// Round 8
// 1914.183 us; speedup vs baseline: 1.1658x; 1.1658x over previous
//
#include <hip/hip_runtime.h>
#include <cmath>
#include <cstdint>

#define NT 256
#define EG0 1024          // grid for full-E passes
#define EG1 256           // grid for compacted passes
#define MAX_ROUND 16      // rounds 0..15 (round0 specialized, 1..15 gated)
#define SCAN_T 32
#define SCAN_IPB (NT*SCAN_T)
#define SENT 0x80000000u  // -0.0f sentinel for "no edge touched this cell"

// ---------- helpers ----------

// Block-aggregated stream compaction append: ONE global atomic per block-tile.
__device__ __forceinline__ int block_append(int* cursor, bool pred, int* s_w){
  int wid  = threadIdx.x >> 6;
  int lane = threadIdx.x & 63;
  unsigned long long m = __ballot(pred);
  int cnt = __popcll(m);
  if(lane==0) s_w[wid]=cnt;
  __syncthreads();
  if(threadIdx.x==0){
    int t0=s_w[0], t1=s_w[1], t2=s_w[2], t3=s_w[3];
    int tot=t0+t1+t2+t3;
    int base = tot ? atomicAdd(cursor, tot) : 0;
    s_w[0]=base; s_w[1]=base+t0; s_w[2]=base+t0+t1; s_w[3]=base+t0+t1+t2;
  }
  __syncthreads();
  int pos = s_w[wid] + __popcll(m & ((1ull<<lane)-1ull));
  __syncthreads();
  return pos;
}

// ---------- init ----------

__global__ void k_init(int* a, int* b, int n){
  int v = blockIdx.x*NT + threadIdx.x;
  if(v<n){ a[v]=v; b[v]=v; }
}

__global__ void k_fill_dense(float* dense, long M){
  long stride = (long)gridDim.x*NT;
  for(long i = (long)blockIdx.x*NT + threadIdx.x; i<M; i+=stride)
    ((unsigned int*)dense)[i] = SENT;
}

// ---------- round 0 (full edge arrays) ----------

__global__ void k_hop0(int* b, const int* __restrict__ row,
                       const int* __restrict__ col, int E){
  int stride = gridDim.x*NT;
  for(int e = blockIdx.x*NT + threadIdx.x; e<E; e+=stride){
    int s = row[e];
    if(s < b[col[e]]) atomicMin(&b[col[e]], s);
  }
}

__global__ void k_hop0f(int* a, const int* b, const int* __restrict__ row,
                        const int* __restrict__ col, int n, int E){
  int stride = gridDim.x*NT;
  int total = n + E;
  for(int i = blockIdx.x*NT + threadIdx.x; i<total; i+=stride){
    if(i<n){
      if(b[i] < a[i]) atomicMin(&a[i], b[i]);
    } else {
      int e = i-n;
      int s = b[row[e]];
      if(s < a[col[e]]) atomicMin(&a[col[e]], s);
    }
  }
}

__global__ void k_dil0(const int* a, int* d2, int* cover, const int* __restrict__ row,
                       const int* __restrict__ col, int E, int ep){
  int stride = gridDim.x*NT;
  for(int e = blockIdx.x*NT + threadIdx.x; e<E; e+=stride){
    int r = row[e];
    if(a[r]==r){
      int cc = col[e];
      d2[r]=ep;  cover[r]=1;
      d2[cc]=ep; cover[cc]=1;
    }
  }
}

__global__ void k_dil20(const int* a, const int* d2, int* cover, const int* __restrict__ row,
                        const int* __restrict__ col, int E, int ep){
  int stride = gridDim.x*NT;
  for(int e = blockIdx.x*NT + threadIdx.x; e<E; e+=stride){
    int r = row[e];
    if((d2[r]==ep || a[r]==r) && !cover[col[e]]) cover[col[e]]=1;
  }
}

// finalize nodes + build U1 + compact edges -> LB (runs AFTER cover settled)
__global__ void k_fincomp0(int* a, int* b, int* mis, int* cover, int n,
                           const int* __restrict__ row, const int* __restrict__ col, int E,
                           int2* Ld, int* lcnt1, int* U1, int* rcnt0){
  __shared__ int s_w[4];
  long nth = (long)gridDim.x*NT;
  for(long base = (long)blockIdx.x*NT; base < n; base += nth){
    int v = (int)base + threadIdx.x;
    bool unc = false;
    if(v<n){
      int nw = (a[v]==v);
      if(nw){ mis[v]=1; if(!cover[v]) cover[v]=1; }
      int cov = cover[v] | nw;
      int val = cov ? n : v;
      a[v]=val; b[v]=val;
      unc = !cov;
    }
    int pos = block_append(rcnt0, unc, s_w);
    if(unc) U1[pos]=v;
  }
  for(long base = (long)blockIdx.x*NT; base < E; base += nth){
    int e = (int)base + threadIdx.x;
    bool keep=false; int2 ed;
    if(e<E){
      ed = make_int2(row[e], col[e]);
      keep = (!cover[ed.x]) || (!cover[ed.y]);
    }
    int pos = block_append(lcnt1, keep, s_w);
    if(keep) Ld[pos]=ed;
  }
}

// ---------- rounds >=1 (compacted list, frontier list, gated) ----------

__global__ void k_hop1(int* b, const int* a, const int2* L, const int* pE,
                       const int* gate){
  if(*gate==0) return;
  int E = *pE;
  int stride = gridDim.x*NT;
  for(int e = blockIdx.x*NT + threadIdx.x; e<E; e+=stride){
    int2 ed = L[e];
    int s = a[ed.x];
    if(s < b[ed.y]) atomicMin(&b[ed.y], s);
  }
}

__global__ void k_hop1f(int* a, const int* b, const int2* L, const int* pE,
                        const int* U, const int* pU, const int* gate){
  if(*gate==0) return;
  int E = *pE, un = *pU;
  int total = un + E;
  int stride = gridDim.x*NT;
  for(int i = blockIdx.x*NT + threadIdx.x; i<total; i+=stride){
    if(i<un){
      int u = U[i];
      if(b[u] < a[u]) atomicMin(&a[u], b[u]);
    } else {
      int2 ed = L[i-un];
      int s = b[ed.x];
      if(s < a[ed.y]) atomicMin(&a[ed.y], s);
    }
  }
}

__global__ void k_dil11(const int* a, int* d2, int* cover, int* mis, const int2* L,
                        const int* pE, const int* U, const int* pU, const int* gate, int ep){
  if(*gate==0) return;
  int E = *pE, un = *pU;
  int total = un + E;
  int stride = gridDim.x*NT;
  for(int i = blockIdx.x*NT + threadIdx.x; i<total; i+=stride){
    if(i<un){
      int u = U[i];
      if(a[u]==u){ mis[u]=1; cover[u]=1; d2[u]=ep; }
    } else {
      int2 ed = L[i-un];
      if(a[ed.x]==ed.x){ d2[ed.x]=ep; cover[ed.x]=1; d2[ed.y]=ep; cover[ed.y]=1; }
    }
  }
}

__global__ void k_dil21(const int* a, const int* d2, int* cover, const int2* L,
                        const int* pE, const int* gate, int ep){
  if(*gate==0) return;
  int E = *pE;
  int stride = gridDim.x*NT;
  for(int e = blockIdx.x*NT + threadIdx.x; e<E; e+=stride){
    int2 ed = L[e];
    if((d2[ed.x]==ep || a[ed.x]==ed.x) && !cover[ed.y]) cover[ed.y]=1;
  }
}

// finalize: reset endpoints from final cover; recompact U and L (ping-pong)
__global__ void k_fincomp1(int* a, int* b, const int* cover, int n,
                           const int2* Ls, const int* pE, int2* Ld, int* lcntD,
                           const int* Us, const int* pU, int* Ud, int* rcntD,
                           const int* gate){
  if(*gate==0) return;
  __shared__ int s_w[4];
  int E = *pE, un = *pU;
  long nth = (long)gridDim.x*NT;
  for(long base = (long)blockIdx.x*NT; base < un; base += nth){
    int i = (int)base + threadIdx.x;
    bool unc=false; int u=0;
    if(i<un){ u = Us[i]; unc = !cover[u]; }
    int pos = block_append(rcntD, unc, s_w);
    if(unc) Ud[pos]=u;
  }
  for(long base = (long)blockIdx.x*NT; base < E; base += nth){
    int e = (int)base + threadIdx.x;
    bool keep=false; int2 ed;
    if(e<E){
      ed = Ls[e];
      int vx = cover[ed.x] ? n : ed.x;  a[ed.x]=vx; b[ed.x]=vx;
      int vy = cover[ed.y] ? n : ed.y;  a[ed.y]=vy; b[ed.y]=vy;
      keep = (!cover[ed.x]) || (!cover[ed.y]);
    }
    int pos = block_append(lcntD, keep, s_w);
    if(keep) Ld[pos]=ed;
  }
}

// ---------- cluster phase ----------

__global__ void k_cluster_init(const int* mis, int* a, int* b, int n){
  int v = blockIdx.x*NT + threadIdx.x;
  if(v<n){ int m = mis[v] ? v : n; a[v]=m; b[v]=m; }
}

__global__ void k_chop1(int* b, const int* a, const int* __restrict__ row,
                        const int* __restrict__ col, int n, int E){
  int stride = gridDim.x*NT;
  for(int e = blockIdx.x*NT + threadIdx.x; e<E; e+=stride){
    int s = a[row[e]];
    if(s < n && s < b[col[e]]) atomicMin(&b[col[e]], s);
  }
}

__global__ void k_chop2f(int* a, const int* b, const int* __restrict__ row,
                         const int* __restrict__ col, int n, int E){
  int stride = gridDim.x*NT;
  int total = n + E;
  for(int i = blockIdx.x*NT + threadIdx.x; i<total; i+=stride){
    if(i<n){
      if(b[i] < a[i]) atomicMin(&a[i], b[i]);
    } else {
      int e = i-n;
      int s = b[row[e]];
      if(s < n && s < a[col[e]]) atomicMin(&a[col[e]], s);
    }
  }
}

__global__ void k_mark(const int* mr, const int* mis, int* present, int* cmis, int n){
  int v = blockIdx.x*NT + threadIdx.x;
  int m = 0;
  if(v<n){
    int r = mr[v];
    if(r<n) present[r]=1;
    m = mis[v];
  }
  __shared__ int sh[NT];
  sh[threadIdx.x]=m; __syncthreads();
  for(int off=NT/2; off>0; off>>=1){
    if(threadIdx.x<off) sh[threadIdx.x]+=sh[threadIdx.x+off];
    __syncthreads();
  }
  if(threadIdx.x==0 && sh[0]) atomicAdd(cmis, sh[0]);
}

// ---------- generic scan ----------

__global__ void k_scan1(const int* A, int M, int* bsum){
  int t = threadIdx.x;
  long base = (long)blockIdx.x*SCAN_IPB + (long)t*SCAN_T;
  int s = 0;
  #pragma unroll
  for(int j=0;j<SCAN_T;j++){ long i=base+j; if(i<M) s += A[i]; }
  __shared__ int sh[NT];
  sh[t]=s; __syncthreads();
  for(int off=NT/2; off>0; off>>=1){ if(t<off) sh[t]+=sh[t+off]; __syncthreads(); }
  if(t==0) bsum[blockIdx.x]=sh[0];
}

__global__ void k_scan2(const int* bsum, int* bscan, int B, int* totalOut){
  __shared__ int sh[NT];
  int t = threadIdx.x;
  int carry = 0;
  for(int base=0; base<B; base+=NT){
    int i = base+t;
    int v = (i<B) ? bsum[i] : 0;
    sh[t]=v; __syncthreads();
    for(int off=1; off<NT; off<<=1){
      int x=0; if(t>=off) x=sh[t-off];
      __syncthreads();
      sh[t]+=x; __syncthreads();
    }
    int incl = sh[t];
    if(i<B) bscan[i] = carry + incl - v;
    carry += sh[NT-1];
    __syncthreads();
  }
  if(t==0 && totalOut) *totalOut = carry;
}

__global__ void k_scan3(const int* A, int M, const int* bscan, int* pref){
  int t = threadIdx.x;
  long base = (long)blockIdx.x*SCAN_IPB + (long)t*SCAN_T;
  int s = 0;
  #pragma unroll
  for(int j=0;j<SCAN_T;j++){ long i=base+j; if(i<M) s += A[i]; }
  __shared__ int sh[NT];
  sh[t]=s; __syncthreads();
  for(int off=1; off<NT; off<<=1){
    int x=0; if(t>=off) x=sh[t-off];
    __syncthreads();
    sh[t]+=x; __syncthreads();
  }
  int run = bscan[blockIdx.x] + (sh[t]-s);
  for(int j=0;j<SCAN_T;j++){
    long i=base+j;
    if(i<M){ pref[i]=run; run += A[i]; }
  }
}

// ---------- clustering & pooling ----------

__global__ void k_assign(const int* mr, const int* pref, int* cl, int* ccount, int n){
  int v = blockIdx.x*NT + threadIdx.x;
  if(v<n){
    int r = mr[v];
    int cid = (r<n) ? pref[r] : 0;
    cl[v]=cid;
    atomicAdd(&ccount[cid],1);
  }
}

__global__ void k_scatter_nodes(const int* cl, const int* cstart, int* cursor, int* nodeList, int n){
  int v = blockIdx.x*NT + threadIdx.x;
  if(v<n){
    int cid = cl[v];
    int pos = cstart[cid] + atomicAdd(&cursor[cid],1);
    nodeList[pos]=v;
  }
}

__global__ void k_pool_x(const float* __restrict__ x, const int* nodeList, const int* cstart,
                         const int* ccount, const int* scal, float* out, long out_size){
  int c = scal[0], U = scal[1];
  int t = threadIdx.x;
  for(int cid=blockIdx.x; cid<c; cid+=gridDim.x){
    float s0=0.f, s1=0.f, s2=0.f, s3=0.f;
    if(cid<U){
      int st = cstart[cid], cn = ccount[cid];
      int i=0;
      for(; i+3<cn; i+=4){
        int n0=nodeList[st+i], n1=nodeList[st+i+1], n2=nodeList[st+i+2], n3=nodeList[st+i+3];
        s0 += x[(size_t)n0*256 + t];
        s1 += x[(size_t)n1*256 + t];
        s2 += x[(size_t)n2*256 + t];
        s3 += x[(size_t)n3*256 + t];
      }
      for(; i<cn; i++) s0 += x[(size_t)nodeList[st+i]*256 + t];
      s0 += s1+s2+s3;
    }
    long idx = (long)cid*256 + t;
    if(idx < out_size) out[idx]=s0;
  }
}

// one fp32 atomic per edge; presence = bit pattern != SENT (-0.0 + x == x)
__global__ void k_edge_pool(const int* __restrict__ row, const int* __restrict__ col,
                            const float* __restrict__ attr, const int* cl,
                            const int* scal, float* dense, int E, long CMsq){
  int c = scal[0];
  int stride = gridDim.x*NT;
  for(int e = blockIdx.x*NT + threadIdx.x; e<E; e+=stride){
    long key = (long)cl[row[e]]*c + cl[col[e]];
    if(key < CMsq){
      unsafeAtomicAdd(&dense[key], attr[e]);
    }
  }
}

__device__ __forceinline__ int cellp(const float* dense, long i){
  return __float_as_uint(dense[i]) != SENT;
}

__global__ void k_cscan1(const float* dense, const int* scal, int* bsum, long CMsq){
  int c = scal[0];
  long M = (long)c*c; if(M>CMsq) M=CMsq;
  int t = threadIdx.x;
  long base = (long)blockIdx.x*SCAN_IPB + (long)t*SCAN_T;
  int s = 0;
  if(base < M && c > 0){
    int r = (int)(base / c);
    int q = (int)(base - (long)r*c);
    for(int j=0;j<SCAN_T;j++){
      long i=base+j;
      if(i<M){
        if(cellp(dense,i) && r!=q) s++;
      }
      if(++q==c){ q=0; r++; }
    }
  }
  __shared__ int sh[NT];
  sh[t]=s; __syncthreads();
  for(int off=NT/2; off>0; off>>=1){ if(t<off) sh[t]+=sh[t+off]; __syncthreads(); }
  if(t==0) bsum[blockIdx.x]=sh[0];
}

__global__ void k_cemit(const float* dense, const int* scal,
                        const int* bscan, float* out, long out_size, long CMsq){
  int c = scal[0]; int P = scal[2];
  long M = (long)c*c; if(M>CMsq) M=CMsq;
  long xoff = (long)c*256;
  int t = threadIdx.x;
  long base = (long)blockIdx.x*SCAN_IPB + (long)t*SCAN_T;
  int s = 0;
  int r0=0,q0=0;
  if(base < M && c > 0){
    r0 = (int)(base / c);
    q0 = (int)(base - (long)r0*c);
    int r=r0, q=q0;
    for(int j=0;j<SCAN_T;j++){
      long i=base+j;
      if(i<M){
        if(cellp(dense,i) && r!=q) s++;
      }
      if(++q==c){ q=0; r++; }
    }
  }
  __shared__ int sh[NT];
  sh[t]=s; __syncthreads();
  for(int off=1; off<NT; off<<=1){
    int x=0; if(t>=off) x=sh[t-off];
    __syncthreads();
    sh[t]+=x; __syncthreads();
  }
  int run = bscan[blockIdx.x] + (sh[t]-s);
  if(base < M && c > 0){
    int r=r0, q=q0;
    for(int j=0;j<SCAN_T;j++){
      long i=base+j;
      if(i<M && cellp(dense,i) && r!=q){
        long o0 = xoff + run;
        long o1 = xoff + (long)P + run;
        long o2 = xoff + 2L*(long)P + run;
        if(o0<out_size) out[o0]=(float)r;
        if(o1<out_size) out[o1]=(float)q;
        if(o2<out_size) out[o2]=dense[i];
        run++;
      }
      if(++q==c){ q=0; r++; }
    }
  }
}

// ---------- host ----------

extern "C" void kernel_launch(void* const* d_in, const int* in_sizes, int n_in,
                              void* d_out, int out_size, void* d_ws, size_t ws_size,
                              hipStream_t stream){
  (void)n_in;
  const float* x     = (const float*)d_in[0];
  const int*   eidx  = (const int*)d_in[1];
  const float* eattr = (const float*)d_in[2];
  const int D = 256;
  int n = in_sizes[0]/D;
  int E = in_sizes[1]/2;
  const int* row = eidx;
  const int* col = eidx + E;

  char* p = (char*)d_ws;
  auto alloc = [&](size_t bytes)->char*{ char* r=p; p += (bytes+255)&~(size_t)255; return r; };
  int2* LA   = (int2*)alloc((size_t)E*8);
  int2* LB   = (int2*)alloc((size_t)E*8);
  int* a     = (int*)alloc((size_t)n*4);
  int* b     = (int*)alloc((size_t)n*4);
  int* cl    = (int*)alloc((size_t)n*4);
  int* nodeList = (int*)alloc((size_t)n*4);
  int* pref  = (int*)alloc((size_t)n*4);
  int* U1    = (int*)alloc((size_t)n*4);
  int* U2    = (int*)alloc((size_t)n*4);
  int* bsum  = (int*)alloc(4096*4);
  int* bscan = (int*)alloc(4096*4);
  char* zstart = p;                         // zeroed each call
  int* mis     = (int*)alloc((size_t)n*4);
  int* cover   = (int*)alloc((size_t)n*4);
  int* d2      = (int*)alloc((size_t)n*4);
  int* present = (int*)alloc((size_t)n*4);
  int* ccount  = (int*)alloc((size_t)n*4);
  int* cursor  = (int*)alloc((size_t)n*4);
  int* rcnt    = (int*)alloc((MAX_ROUND+2)*4);
  int* lcnt    = (int*)alloc((MAX_ROUND+2)*4);
  int* scal    = (int*)alloc(64);              // [0]=c, [1]=U, [2]=P
  size_t zbytes = (size_t)(p - zstart);

  size_t used   = (size_t)(p-(char*)d_ws);
  size_t remain = (ws_size > used+4096) ? ws_size-used-4096 : 0;
  size_t cells  = remain/4;
  long CM = (long)std::sqrt((double)cells);
  while(CM>1 && CM*CM > (long)cells) CM--;
  if(CM>4096) CM=4096;
  if(CM<1) CM=1;
  long CMsq = CM*CM;
  float* dense = (float*)alloc((size_t)CMsq*4);

  hipMemsetAsync(zstart, 0, zbytes, stream);
  k_fill_dense<<<2048,NT,0,stream>>>(dense, CMsq);

  int NB  = (n+NT-1)/NT;
  int NBs = (n+SCAN_IPB-1)/SCAN_IPB;
  int CB  = (int)((CMsq+SCAN_IPB-1)/SCAN_IPB);

  // ---- round 0 (full graph) ----
  k_init    <<<NB,NT,0,stream>>>(a,b,n);
  k_hop0    <<<EG0,NT,0,stream>>>(b,row,col,E);
  k_hop0f   <<<EG0,NT,0,stream>>>(a,b,row,col,n,E);
  k_dil0    <<<EG0,NT,0,stream>>>(a,d2,cover,row,col,E,1);
  k_dil20   <<<EG0,NT,0,stream>>>(a,d2,cover,row,col,E,1);
  k_fincomp0<<<EG0,NT,0,stream>>>(a,b,mis,cover,n,row,col,E,LB,&lcnt[1],U1,&rcnt[0]);

  // ---- rounds 1..MAX_ROUND-1 (compacted, gated on rcnt[r-1]) ----
  for(int r=1; r<MAX_ROUND; ++r){
    int2* Ls = (r&1) ? LB : LA;
    int2* Ld = (r&1) ? LA : LB;
    int*  Us = (r&1) ? U1 : U2;
    int*  Ud = (r&1) ? U2 : U1;
    int ep = r+1;
    k_hop1    <<<EG1,NT,0,stream>>>(b,a,Ls,&lcnt[r],&rcnt[r-1]);
    k_hop1f   <<<EG1,NT,0,stream>>>(a,b,Ls,&lcnt[r],Us,&rcnt[r-1],&rcnt[r-1]);
    k_dil11   <<<EG1,NT,0,stream>>>(a,d2,cover,mis,Ls,&lcnt[r],Us,&rcnt[r-1],&rcnt[r-1],ep);
    k_dil21   <<<EG1,NT,0,stream>>>(a,d2,cover,Ls,&lcnt[r],&rcnt[r-1],ep);
    k_fincomp1<<<EG1,NT,0,stream>>>(a,b,cover,n,Ls,&lcnt[r],Ld,&lcnt[r+1],
                                    Us,&rcnt[r-1],Ud,&rcnt[r],&rcnt[r-1]);
  }

  // ---- cluster propagation ----
  k_cluster_init<<<NB,NT,0,stream>>>(mis,a,b,n);
  k_chop1 <<<EG0,NT,0,stream>>>(b,a,row,col,n,E);
  k_chop2f<<<EG0,NT,0,stream>>>(a,b,row,col,n,E);

  // ---- unique -> cluster ids ----
  k_mark <<<NB,NT,0,stream>>>(a,mis,present,scal,n);
  k_scan1<<<NBs,NT,0,stream>>>(present,n,bsum);
  k_scan2<<<1,NT,0,stream>>>(bsum,bscan,NBs,scal+1);
  k_scan3<<<NBs,NT,0,stream>>>(present,n,bscan,pref);
  k_assign<<<NB,NT,0,stream>>>(a,pref,cl,ccount,n);

  // ---- counting sort by cluster ----
  k_scan1<<<NBs,NT,0,stream>>>(ccount,n,bsum);
  k_scan2<<<1,NT,0,stream>>>(bsum,bscan,NBs,nullptr);
  k_scan3<<<NBs,NT,0,stream>>>(ccount,n,bscan,pref);
  k_scatter_nodes<<<NB,NT,0,stream>>>(cl,pref,cursor,nodeList,n);

  // ---- x_pooled ----
  k_pool_x<<<1024,NT,0,stream>>>(x,nodeList,pref,ccount,scal,(float*)d_out,(long)out_size);

  // ---- pooled adjacency ----
  k_edge_pool<<<EG0,NT,0,stream>>>(row,col,eattr,cl,scal,dense,E,CMsq);
  k_cscan1<<<CB,NT,0,stream>>>(dense,scal,bsum,CMsq);
  k_scan2 <<<1,NT,0,stream>>>(bsum,bscan,CB,scal+2);
  k_cemit <<<CB,NT,0,stream>>>(dense,scal,bscan,(float*)d_out,(long)out_size,CMsq);
}